// Round 14
// baseline (135.363 us; speedup 1.0000x reference)
//
#include <hip/hip_runtime.h>
#include <float.h>

// VectorQuantizer on MI355X — MFMA f16 screen + windowed bit-exact np-f32 rescue.
//
// R4-R13 established: (1) idx must replicate numpy-f32 rounding exactly (R4);
// (2) screen+rescue with W=0.5 scaled window is numerically safe (R13 passed);
// (3) the VALU path is stuck at ~50% duty because the e-operand stream via
// s_load can't be pipelined (one k-group = 128 SGPRs > budget) — R7-R13 all
// ~90-97us. R14 moves the screen onto the idle matrix pipe (MfmaUtil was 0.0
// all session): S = -2 X.E^T + 512*t2 via mfma_f32_16x16x32_f16, u = 512e
// (pow2-exact scale; f16 conv err bound ~0.1 scaled << W=0.5).
// Pass1 = min only; Pass2 = recompute MFMA (cheap; avoids spill-prone s-array)
// and rescue candidates (s < min+W, ~1.3/pixel) through the EXACT R4 np-f32
// chain with explicit (dist,k) tiebreak == numpy first-argmin.
// C-fragment mapping (m89-verified): col=lane&15 (pixel), row=(lane>>4)*4+j (code).
#pragma clang fp contract(off)

#define K_EMB   512
#define D_EMB   64
#define Q_ELEMS 4194304   // 64 * 64 * 32 * 32
#define NBLK    1024      // 64 pixels per block
#define W_SCR   0.5f      // rescue window, scaled (512x) units — validated R13
#define XPAD    72        // xh row stride in f16 (144B = 16B-aligned rows)

typedef _Float16 f16x8 __attribute__((ext_vector_type(8)));
typedef float    f32x4 __attribute__((ext_vector_type(4)));

// numpy pairwise_sum order for n=64 contiguous f32, summing PRE-ROUNDED squares.
__device__ __forceinline__ float np_sumsq64(const float* __restrict__ v) {
    float r[8];
    #pragma unroll
    for (int j = 0; j < 8; ++j) r[j] = v[j] * v[j];
    #pragma unroll
    for (int i = 8; i < 64; i += 8) {
        #pragma unroll
        for (int j = 0; j < 8; ++j) {
            float s = v[i + j] * v[i + j];
            r[j] = r[j] + s;
        }
    }
    return ((r[0] + r[1]) + (r[2] + r[3])) + ((r[4] + r[5]) + (r[6] + r[7]));
}

// exact np-f32 distance for code k (rare rescue path; R4-proven chain)
__device__ __noinline__ float np_dist(const float* __restrict__ xp,
                                      const float* __restrict__ emb,
                                      const float* __restrict__ t2,
                                      int k) {
    float xv[D_EMB];
    #pragma unroll
    for (int d = 0; d < D_EMB; ++d) xv[d] = xp[d * 1024];
    const float t1 = np_sumsq64(xv);
    const float* __restrict__ ep = emb + (k << 6);
    float a = 0.f;
    #pragma unroll
    for (int d = 0; d < D_EMB; ++d) a = fmaf(xv[d], ep[d], a);
    float X = t1 + t2[k];
    return fmaf(-2.f, a, X);
}

// ---------------- kernel 1: t2 (np-exact), 512^2-scaled t2, A-fragment table ----
// embA layout: flat slot g = (t*2+s)*64 + l holds 8 f16: lane l's A-fragment for
// code tile t, k-step s: code = t*16+(l&15), dims d = s*32+(l>>4)*8 .. +8, u=512e.
__global__ __launch_bounds__(256) void vq_prep(const float* __restrict__ emb,
                                               float* __restrict__ t2,
                                               float* __restrict__ t2s512,
                                               f16x8* __restrict__ embA) {
    const int g = blockIdx.x * 256 + threadIdx.x;
    if (g < K_EMB) {
        const float* ep = emb + (g << 6);
        float e[D_EMB];
        #pragma unroll
        for (int j = 0; j < D_EMB; ++j) e[j] = ep[j];
        float s = np_sumsq64(e);
        t2[g]     = s;
        t2s512[g] = 512.0f * s;                 // pow2 scale: exact
    }
    if (g < 4096) {
        const int t = g >> 7;
        const int s = (g >> 6) & 1;
        const int l = g & 63;
        const int code  = t * 16 + (l & 15);
        const int dbase = s * 32 + ((l >> 4) << 3);
        const float* ep = emb + (code << 6) + dbase;
        f16x8 a;
        #pragma unroll
        for (int i = 0; i < 8; ++i) a[i] = (_Float16)(512.0f * ep[i]);
        embA[g] = a;
    }
}

// ---------------- kernel 2: main VQ (MFMA screen + rescue) ----------------
__global__ __launch_bounds__(256) void vq_main(const float* __restrict__ x,
                                               const float* __restrict__ emb,
                                               const float* __restrict__ t2,
                                               const float* __restrict__ t2s512,
                                               const f16x8* __restrict__ embA,
                                               float* __restrict__ out_q,
                                               float* __restrict__ out_idx,
                                               float* __restrict__ partial) {
    const int tid  = threadIdx.x;
    const int lane = tid & 63;
    const int wave = tid >> 6;                  // 0..3: wave w owns pixels 16w..16w+15

    __shared__ _Float16 xh[64][XPAD];           // f16 x-tile, 16B-aligned rows
    __shared__ int      kwin[64];
    __shared__ float    red[4];

    // ---- stage: 256 threads, thread t -> pixel t&63, dims quarter (t>>6)*16 ----
    {
        const int p = tid & 63;
        const int q = tid >> 6;
        const int np_ = blockIdx.x * 64 + p;
        const float* __restrict__ xs = x + (np_ >> 10) * 65536 + (np_ & 1023);
        #pragma unroll
        for (int j = 0; j < 16; ++j) {
            const int d = q * 16 + j;
            xh[p][d] = (_Float16)xs[d * 1024];
        }
    }
    __syncthreads();

    // ---- B-fragments for this wave's 16 pixels (held in 8 VGPRs) ----
    const int bp = 16 * wave + (lane & 15);     // pixel row in xh
    const int bg = lane >> 4;                   // k-slice group
    const f16x8 b0 = *(const f16x8*)&xh[bp][0 * 32 + bg * 8];
    const f16x8 b1 = *(const f16x8*)&xh[bp][1 * 32 + bg * 8];

    const f32x4 czero = {0.f, 0.f, 0.f, 0.f};
    const float4* __restrict__ t2s4 = (const float4*)t2s512;

    // ---- pass 1: screen min over all 512 codes ----
    float m = FLT_MAX;
    for (int t = 0; t < 32; ++t) {
        f16x8 a0 = embA[(t * 2 + 0) * 64 + lane];
        f16x8 a1 = embA[(t * 2 + 1) * 64 + lane];
        f32x4 c = __builtin_amdgcn_mfma_f32_16x16x32_f16(a0, b0, czero, 0, 0, 0);
        c = __builtin_amdgcn_mfma_f32_16x16x32_f16(a1, b1, c, 0, 0, 0);
        float4 tv = t2s4[t * 4 + bg];
        float s0 = fmaf(-2.f, c[0], tv.x);
        float s1 = fmaf(-2.f, c[1], tv.y);
        float s2 = fmaf(-2.f, c[2], tv.z);
        float s3 = fmaf(-2.f, c[3], tv.w);
        m = fminf(m, fminf(fminf(s0, s1), fminf(s2, s3)));
    }
    // per-pixel global min across the 4 lane-groups holding this pixel
    m = fminf(m, __shfl_xor(m, 16));
    m = fminf(m, __shfl_xor(m, 32));
    const float thr = m + W_SCR;

    // ---- pass 2: recompute screen, rescue candidates with exact np-f32 ----
    const int np_ = blockIdx.x * 64 + bp;       // this lane's pixel
    const float* __restrict__ xp = x + (np_ >> 10) * 65536 + (np_ & 1023);
    float bnp = FLT_MAX;
    int   bk  = 0x7fffffff;
    for (int t = 0; t < 32; ++t) {
        f16x8 a0 = embA[(t * 2 + 0) * 64 + lane];
        f16x8 a1 = embA[(t * 2 + 1) * 64 + lane];
        f32x4 c = __builtin_amdgcn_mfma_f32_16x16x32_f16(a0, b0, czero, 0, 0, 0);
        c = __builtin_amdgcn_mfma_f32_16x16x32_f16(a1, b1, c, 0, 0, 0);
        float4 tv = t2s4[t * 4 + bg];
        #pragma unroll
        for (int j = 0; j < 4; ++j) {
            float sj = fmaf(-2.f, c[j], (j == 0) ? tv.x : (j == 1) ? tv.y
                                       : (j == 2) ? tv.z : tv.w);
            if (sj < thr) {
                const int k = t * 16 + bg * 4 + j;
                float dnp = np_dist(xp, emb, t2, k);
                if (dnp < bnp || (dnp == bnp && k < bk)) { bnp = dnp; bk = k; }
            }
        }
    }
    // merge the 4 lane-groups of this pixel (explicit k tiebreak == np first-min)
    {
        float d1 = __shfl_xor(bnp, 16); int k1 = __shfl_xor(bk, 16);
        if (d1 < bnp || (d1 == bnp && k1 < bk)) { bnp = d1; bk = k1; }
        float d2 = __shfl_xor(bnp, 32); int k2 = __shfl_xor(bk, 32);
        if (d2 < bnp || (d2 == bnp && k2 < bk)) { bnp = d2; bk = k2; }
    }
    if (bg == 0) kwin[bp] = bk;
    __syncthreads();

    // ---- epilogue: 256 threads, thread t -> pixel t&63, dims quarter t>>6 ----
    float acc = 0.f;
    {
        const int p = tid & 63;
        const int q = tid >> 6;
        const int n2 = blockIdx.x * 64 + p;
        const int kw = kwin[p];
        const float* __restrict__ xs = x + (n2 >> 10) * 65536 + (n2 & 1023);
        float* __restrict__ qp = out_q + (n2 >> 10) * 65536 + (n2 & 1023);
        const float4* __restrict__ eq = (const float4*)(emb + (kw << 6) + q * 16);
        #pragma unroll
        for (int j4 = 0; j4 < 4; ++j4) {
            float4 qv = eq[j4];
            const int d = q * 16 + j4 * 4;
            float f0 = qv.x - xs[(d + 0) * 1024];
            float f1 = qv.y - xs[(d + 1) * 1024];
            float f2 = qv.z - xs[(d + 2) * 1024];
            float f3 = qv.w - xs[(d + 3) * 1024];
            acc = fmaf(f0, f0, acc);
            acc = fmaf(f1, f1, acc);
            acc = fmaf(f2, f2, acc);
            acc = fmaf(f3, f3, acc);
            qp[(d + 0) * 1024] = qv.x;
            qp[(d + 1) * 1024] = qv.y;
            qp[(d + 2) * 1024] = qv.z;
            qp[(d + 3) * 1024] = qv.w;
        }
        if (q == 0) out_idx[n2] = (float)kw;
    }

    // block loss partial: deterministic wave shuffle + LDS reduce
    #pragma unroll
    for (int off = 32; off > 0; off >>= 1) acc += __shfl_down(acc, off);
    if (lane == 0) red[wave] = acc;
    __syncthreads();
    if (tid == 0)
        partial[blockIdx.x] = (red[0] + red[1]) + (red[2] + red[3]);
}

// ---------------- kernel 3: finalize loss over 1024 partials ----------------
__global__ __launch_bounds__(256) void vq_loss(const float* __restrict__ partial,
                                               float* __restrict__ loss) {
    const int t = threadIdx.x;
    float v = (partial[t] + partial[t + 256]) + (partial[t + 512] + partial[t + 768]);
    #pragma unroll
    for (int off = 32; off > 0; off >>= 1) v += __shfl_down(v, off);
    __shared__ float red[4];
    if ((t & 63) == 0) red[t >> 6] = v;
    __syncthreads();
    if (t == 0)
        loss[0] = 1.25f * ((red[0] + red[1]) + (red[2] + red[3])) / (float)Q_ELEMS;
}

extern "C" void kernel_launch(void* const* d_in, const int* in_sizes, int n_in,
                              void* d_out, int out_size, void* d_ws, size_t ws_size,
                              hipStream_t stream) {
    const float* x   = (const float*)d_in[0];   // [64,64,32,32] NCHW
    const float* emb = (const float*)d_in[1];   // [512,64]

    float* out_q    = (float*)d_out;                // [4194304]
    float* out_loss = (float*)d_out + Q_ELEMS;      // [1]
    float* out_idx  = (float*)d_out + Q_ELEMS + 1;  // [65536] as float

    float* t2      = (float*)d_ws;                  // 512
    float* t2s512  = t2 + K_EMB;                    // 512
    float* partial = t2s512 + K_EMB;                // 1024
    f16x8* embA    = (f16x8*)(partial + 1024);      // 4096 slots * 16B = 64KB

    vq_prep<<<16, 256, 0, stream>>>(emb, t2, t2s512, embA);
    vq_main<<<NBLK, 256, 0, stream>>>(x, emb, t2, t2s512, embA,
                                      out_q, out_idx, partial);
    vq_loss<<<1, 256, 0, stream>>>(partial, out_loss);
}

// Round 15
// 47.979 us; speedup vs baseline: 2.8213x; 2.8213x over previous
//
#include <hip/hip_runtime.h>
#include <float.h>

// VectorQuantizer on MI355X — MFMA f16 screen + compacted wave-parallel np-f32 rescue.
//
// R14 proved: MFMA screen (mfma_f32_16x16x32_f16, u=512e, W=0.5) is CORRECT
// (absmax unchanged) and cheap (MfmaUtil 2.3% ~ 3us). Its regression to 139us
// was the rescue: per-lane-divergent np_dist calls ran ~19x serialized per wave
// under exec-masking (1-4 active lanes x ~140 VALU + 64 loads each).
// R15: pass2 only COLLECTS candidates (LDS list, ~77/block); after a barrier,
// 256 threads process the list one-candidate-per-lane (full-width rescue).
// Per-pixel numpy-first-min via LDS atomicMin on key=(bits(dist)<<32)|k
// (dists ~64 > 0 -> bit order == float order; ties -> min k). t1 precomputed
// per pixel by wave 0 (np-exact from f32 x). Exact chain per candidate is
// R4-proven: sequential fmaf dot, X=t1+t2[k], fmaf(-2,a,X).
#pragma clang fp contract(off)

#define K_EMB   512
#define D_EMB   64
#define Q_ELEMS 4194304   // 64 * 64 * 32 * 32
#define NBLK    1024      // 64 pixels per block
#define W_SCR   0.5f      // rescue window, scaled (512x) units — validated R13/R14
#define XPAD    72        // xh row stride in f16 (144B = 16B-aligned rows)
#define LCAP    1024      // candidate list capacity (avg ~77/block; huge margin)

typedef _Float16 f16x8 __attribute__((ext_vector_type(8)));
typedef float    f32x4 __attribute__((ext_vector_type(4)));

// numpy pairwise_sum order for n=64 f32 with STRIDE, summing PRE-ROUNDED squares.
__device__ __forceinline__ float np_sumsq64_strided(const float* __restrict__ v,
                                                    int stride) {
    float r[8];
    #pragma unroll
    for (int j = 0; j < 8; ++j) { float a = v[j * stride]; r[j] = a * a; }
    #pragma unroll
    for (int i = 8; i < 64; i += 8) {
        #pragma unroll
        for (int j = 0; j < 8; ++j) {
            float a = v[(i + j) * stride];
            float s = a * a;
            r[j] = r[j] + s;
        }
    }
    return ((r[0] + r[1]) + (r[2] + r[3])) + ((r[4] + r[5]) + (r[6] + r[7]));
}

// ---------------- kernel 1: t2 (np-exact), 512-scaled t2, A-fragment table ----
// embA slot g=(t*2+s)*64+l: lane l's A-frag for code tile t, k-step s:
// code=t*16+(l&15), dims d = s*32+(l>>4)*8 .. +8, values u=512e (pow2-exact).
__global__ __launch_bounds__(256) void vq_prep(const float* __restrict__ emb,
                                               float* __restrict__ t2,
                                               float* __restrict__ t2s512,
                                               f16x8* __restrict__ embA) {
    const int g = blockIdx.x * 256 + threadIdx.x;
    if (g < K_EMB) {
        const float* ep = emb + (g << 6);
        float s = np_sumsq64_strided(ep, 1);
        t2[g]     = s;
        t2s512[g] = 512.0f * s;
    }
    if (g < 4096) {
        const int t = g >> 7;
        const int s = (g >> 6) & 1;
        const int l = g & 63;
        const int code  = t * 16 + (l & 15);
        const int dbase = s * 32 + ((l >> 4) << 3);
        const float* ep = emb + (code << 6) + dbase;
        f16x8 a;
        #pragma unroll
        for (int i = 0; i < 8; ++i) a[i] = (_Float16)(512.0f * ep[i]);
        embA[g] = a;
    }
}

// ---------------- kernel 2: main VQ (MFMA screen + compacted rescue) ----------
__global__ __launch_bounds__(256) void vq_main(const float* __restrict__ x,
                                               const float* __restrict__ emb,
                                               const float* __restrict__ t2,
                                               const float* __restrict__ t2s512,
                                               const f16x8* __restrict__ embA,
                                               float* __restrict__ out_q,
                                               float* __restrict__ out_idx,
                                               float* __restrict__ partial) {
    const int tid  = threadIdx.x;
    const int lane = tid & 63;
    const int wave = tid >> 6;                  // 0..3

    __shared__ _Float16 xh[64][XPAD];           // f16 x-tile
    __shared__ float    t1s[64];                // np-exact t1 per pixel
    __shared__ unsigned long long keys[64];     // (bits(dist)<<32)|k per pixel
    __shared__ int      list[LCAP];             // packed candidates p*512+k
    __shared__ int      lcnt;
    __shared__ float    red[4];

    // ---- stage: xh (all threads), t1 (wave 0), init keys/cnt ----
    {
        const int p = tid & 63;
        const int q = tid >> 6;
        const int np_ = blockIdx.x * 64 + p;
        const float* __restrict__ xs = x + (np_ >> 10) * 65536 + (np_ & 1023);
        #pragma unroll
        for (int j = 0; j < 16; ++j) {
            const int d = q * 16 + j;
            xh[p][d] = (_Float16)xs[d * 1024];
        }
        if (tid < 64) {
            keys[tid] = 0xFFFFFFFFFFFFFFFFull;
            t1s[tid]  = np_sumsq64_strided(xs, 1024);   // q==0 lanes: pixel tid
        }
        if (tid == 0) lcnt = 0;
    }
    __syncthreads();

    // ---- B-fragments for this wave's 16 pixels ----
    const int bp = 16 * wave + (lane & 15);     // pixel row
    const int bg = lane >> 4;                   // code-slice group
    const f16x8 b0 = *(const f16x8*)&xh[bp][0 * 32 + bg * 8];
    const f16x8 b1 = *(const f16x8*)&xh[bp][1 * 32 + bg * 8];

    const f32x4 czero = {0.f, 0.f, 0.f, 0.f};
    const float4* __restrict__ t2s4 = (const float4*)t2s512;

    // ---- pass 1: screen min over all 512 codes ----
    float m = FLT_MAX;
    for (int t = 0; t < 32; ++t) {
        f16x8 a0 = embA[(t * 2 + 0) * 64 + lane];
        f16x8 a1 = embA[(t * 2 + 1) * 64 + lane];
        f32x4 c = __builtin_amdgcn_mfma_f32_16x16x32_f16(a0, b0, czero, 0, 0, 0);
        c = __builtin_amdgcn_mfma_f32_16x16x32_f16(a1, b1, c, 0, 0, 0);
        float4 tv = t2s4[t * 4 + bg];
        float s0 = fmaf(-2.f, c[0], tv.x);
        float s1 = fmaf(-2.f, c[1], tv.y);
        float s2 = fmaf(-2.f, c[2], tv.z);
        float s3 = fmaf(-2.f, c[3], tv.w);
        m = fminf(m, fminf(fminf(s0, s1), fminf(s2, s3)));
    }
    m = fminf(m, __shfl_xor(m, 16));
    m = fminf(m, __shfl_xor(m, 32));
    const float thr = m + W_SCR;                // per-pixel threshold

    // ---- pass 2: recompute screen, COLLECT candidates ----
    for (int t = 0; t < 32; ++t) {
        f16x8 a0 = embA[(t * 2 + 0) * 64 + lane];
        f16x8 a1 = embA[(t * 2 + 1) * 64 + lane];
        f32x4 c = __builtin_amdgcn_mfma_f32_16x16x32_f16(a0, b0, czero, 0, 0, 0);
        c = __builtin_amdgcn_mfma_f32_16x16x32_f16(a1, b1, c, 0, 0, 0);
        float4 tv = t2s4[t * 4 + bg];
        #pragma unroll
        for (int j = 0; j < 4; ++j) {
            float sj = fmaf(-2.f, c[j], (j == 0) ? tv.x : (j == 1) ? tv.y
                                       : (j == 2) ? tv.z : tv.w);
            if (sj < thr) {
                const int k = t * 16 + bg * 4 + j;
                int slot = atomicAdd(&lcnt, 1);
                if (slot < LCAP) list[slot] = bp * 512 + k;
            }
        }
    }
    __syncthreads();

    // ---- rescue: one candidate per lane, full-width parallel ----
    const int ncand = min(lcnt, LCAP);
    for (int i = tid; i < ncand; i += 256) {
        const int v = list[i];
        const int p = v >> 9;
        const int k = v & 511;
        const int np_ = blockIdx.x * 64 + p;
        const float* __restrict__ xp = x + (np_ >> 10) * 65536 + (np_ & 1023);
        const float* __restrict__ ep = emb + (k << 6);
        float a = 0.f;
        #pragma unroll
        for (int d = 0; d < D_EMB; ++d) a = fmaf(xp[d * 1024], ep[d], a);
        float X = t1s[p] + t2[k];
        float dnp = fmaf(-2.f, a, X);           // exact np-f32 dist
        unsigned long long key =
            ((unsigned long long)__float_as_uint(dnp) << 32) | (unsigned)k;
        atomicMin(&keys[p], key);
    }
    __syncthreads();

    // ---- epilogue: thread t -> pixel t&63, dims quarter t>>6 ----
    float acc = 0.f;
    {
        const int p = tid & 63;
        const int q = tid >> 6;
        const int n2 = blockIdx.x * 64 + p;
        const int kw = (int)(unsigned)(keys[p] & 0xFFFFFFFFull);
        const float* __restrict__ xs = x + (n2 >> 10) * 65536 + (n2 & 1023);
        float* __restrict__ qp = out_q + (n2 >> 10) * 65536 + (n2 & 1023);
        const float4* __restrict__ eq = (const float4*)(emb + (kw << 6) + q * 16);
        #pragma unroll
        for (int j4 = 0; j4 < 4; ++j4) {
            float4 qv = eq[j4];
            const int d = q * 16 + j4 * 4;
            float f0 = qv.x - xs[(d + 0) * 1024];
            float f1 = qv.y - xs[(d + 1) * 1024];
            float f2 = qv.z - xs[(d + 2) * 1024];
            float f3 = qv.w - xs[(d + 3) * 1024];
            acc = fmaf(f0, f0, acc);
            acc = fmaf(f1, f1, acc);
            acc = fmaf(f2, f2, acc);
            acc = fmaf(f3, f3, acc);
            qp[(d + 0) * 1024] = qv.x;
            qp[(d + 1) * 1024] = qv.y;
            qp[(d + 2) * 1024] = qv.z;
            qp[(d + 3) * 1024] = qv.w;
        }
        if (q == 0) out_idx[n2] = (float)kw;
    }

    // block loss partial
    #pragma unroll
    for (int off = 32; off > 0; off >>= 1) acc += __shfl_down(acc, off);
    if (lane == 0) red[wave] = acc;
    __syncthreads();
    if (tid == 0)
        partial[blockIdx.x] = (red[0] + red[1]) + (red[2] + red[3]);
}

// ---------------- kernel 3: finalize loss over 1024 partials ----------------
__global__ __launch_bounds__(256) void vq_loss(const float* __restrict__ partial,
                                               float* __restrict__ loss) {
    const int t = threadIdx.x;
    float v = (partial[t] + partial[t + 256]) + (partial[t + 512] + partial[t + 768]);
    #pragma unroll
    for (int off = 32; off > 0; off >>= 1) v += __shfl_down(v, off);
    __shared__ float red[4];
    if ((t & 63) == 0) red[t >> 6] = v;
    __syncthreads();
    if (t == 0)
        loss[0] = 1.25f * ((red[0] + red[1]) + (red[2] + red[3])) / (float)Q_ELEMS;
}

extern "C" void kernel_launch(void* const* d_in, const int* in_sizes, int n_in,
                              void* d_out, int out_size, void* d_ws, size_t ws_size,
                              hipStream_t stream) {
    const float* x   = (const float*)d_in[0];   // [64,64,32,32] NCHW
    const float* emb = (const float*)d_in[1];   // [512,64]

    float* out_q    = (float*)d_out;                // [4194304]
    float* out_loss = (float*)d_out + Q_ELEMS;      // [1]
    float* out_idx  = (float*)d_out + Q_ELEMS + 1;  // [65536] as float

    float* t2      = (float*)d_ws;                  // 512
    float* t2s512  = t2 + K_EMB;                    // 512
    float* partial = t2s512 + K_EMB;                // 1024
    f16x8* embA    = (f16x8*)(partial + 1024);      // 4096 * 16B = 64KB

    vq_prep<<<16, 256, 0, stream>>>(emb, t2, t2s512, embA);
    vq_main<<<NBLK, 256, 0, stream>>>(x, emb, t2, t2s512, embA,
                                      out_q, out_idx, partial);
    vq_loss<<<1, 256, 0, stream>>>(partial, out_loss);
}

// Round 16
// 44.501 us; speedup vs baseline: 3.0418x; 1.0781x over previous
//
#include <hip/hip_runtime.h>
#include <float.h>

// VectorQuantizer on MI355X — MFMA f16 screen + compacted np-f32 rescue, x staged
// once in LDS-f32.
//
// R15 (48us): screen+compaction correct & fast; remaining time is ~85% stalls —
// rescue/t1/epilogue each re-read x via strided global loads (200cy, serial fmaf
// chain can't hide them at VGPR=52). R16: xf[64][65] f32 LDS tile staged once;
// t1 (np-exact, contiguous row), B-frags (same RN f16 cvt), rescue (6cy ds_read
// -> chain pipelines) and epilogue all read LDS. One-shot phases, so R9's
// LDS-pipe-oversubscription doesn't apply. Screen/collect/tiebreak logic
// byte-identical to R15 (passed, absmax 7.6e-6).
#pragma clang fp contract(off)

#define K_EMB   512
#define D_EMB   64
#define Q_ELEMS 4194304   // 64 * 64 * 32 * 32
#define NBLK    1024      // 64 pixels per block
#define W_SCR   0.5f      // rescue window, scaled (512x) — validated R13/R14/R15
#define XROW    65        // xf row stride (odd -> bank-spread)
#define LCAP    1024      // candidate list capacity (avg ~77/block)

typedef _Float16 f16x8 __attribute__((ext_vector_type(8)));
typedef float    f32x4 __attribute__((ext_vector_type(4)));

// numpy pairwise_sum order for n=64 contiguous f32, summing PRE-ROUNDED squares.
__device__ __forceinline__ float np_sumsq64(const float* v) {
    float r[8];
    #pragma unroll
    for (int j = 0; j < 8; ++j) r[j] = v[j] * v[j];
    #pragma unroll
    for (int i = 8; i < 64; i += 8) {
        #pragma unroll
        for (int j = 0; j < 8; ++j) {
            float s = v[i + j] * v[i + j];
            r[j] = r[j] + s;
        }
    }
    return ((r[0] + r[1]) + (r[2] + r[3])) + ((r[4] + r[5]) + (r[6] + r[7]));
}

// ---------------- kernel 1: t2 (np-exact), 512-scaled t2, A-fragment table ----
// embA slot g=(t*2+s)*64+l: lane l's A-frag for code tile t, k-step s:
// code=t*16+(l&15), dims d = s*32+(l>>4)*8 .. +8, values u=512e (pow2-exact).
__global__ __launch_bounds__(256) void vq_prep(const float* __restrict__ emb,
                                               float* __restrict__ t2,
                                               float* __restrict__ t2s512,
                                               f16x8* __restrict__ embA) {
    const int g = blockIdx.x * 256 + threadIdx.x;
    if (g < K_EMB) {
        const float* ep = emb + (g << 6);
        float s = np_sumsq64(ep);
        t2[g]     = s;
        t2s512[g] = 512.0f * s;
    }
    if (g < 4096) {
        const int t = g >> 7;
        const int s = (g >> 6) & 1;
        const int l = g & 63;
        const int code  = t * 16 + (l & 15);
        const int dbase = s * 32 + ((l >> 4) << 3);
        const float* ep = emb + (code << 6) + dbase;
        f16x8 a;
        #pragma unroll
        for (int i = 0; i < 8; ++i) a[i] = (_Float16)(512.0f * ep[i]);
        embA[g] = a;
    }
}

// ---------------- kernel 2: main VQ ----------------
__global__ __launch_bounds__(256) void vq_main(const float* __restrict__ x,
                                               const float* __restrict__ emb,
                                               const float* __restrict__ t2,
                                               const float* __restrict__ t2s512,
                                               const f16x8* __restrict__ embA,
                                               float* __restrict__ out_q,
                                               float* __restrict__ out_idx,
                                               float* __restrict__ partial) {
    const int tid  = threadIdx.x;
    const int lane = tid & 63;
    const int wave = tid >> 6;                  // 0..3

    __shared__ float xf[64 * XROW];             // f32 x-tile, staged ONCE (16.6 KB)
    __shared__ float t1s[64];                   // np-exact t1 per pixel
    __shared__ unsigned long long keys[64];     // (bits(dist)<<32)|k per pixel
    __shared__ int   list[LCAP];                // packed candidates p*512+k
    __shared__ int   lcnt;
    __shared__ float red[4];

    // ---- stage: thread (p,q) loads x[p][16q..16q+15] (coalesced per-d) ----
    {
        const int p = tid & 63;
        const int q = tid >> 6;
        const int np_ = blockIdx.x * 64 + p;
        const float* __restrict__ xs = x + (np_ >> 10) * 65536 + (np_ & 1023);
        #pragma unroll
        for (int j = 0; j < 16; ++j) {
            const int d = q * 16 + j;
            xf[p * XROW + d] = xs[d * 1024];
        }
        if (tid < 64) keys[tid] = 0xFFFFFFFFFFFFFFFFull;
        if (tid == 0) lcnt = 0;
    }
    __syncthreads();

    // ---- wave 0: t1 per pixel (np-exact, contiguous LDS row) ----
    if (wave == 0) t1s[lane] = np_sumsq64(&xf[lane * XROW]);
    // (visible to all by the post-pass2 barrier, before rescue uses it)

    // ---- B-fragments for this wave's 16 pixels (RN f16 cvt from LDS f32) ----
    const int bp = 16 * wave + (lane & 15);     // pixel row
    const int bg = lane >> 4;                   // code-slice group
    f16x8 b0, b1;
    #pragma unroll
    for (int i = 0; i < 8; ++i) {
        b0[i] = (_Float16)xf[bp * XROW + 0 * 32 + bg * 8 + i];
        b1[i] = (_Float16)xf[bp * XROW + 1 * 32 + bg * 8 + i];
    }

    const f32x4 czero = {0.f, 0.f, 0.f, 0.f};
    const float4* __restrict__ t2s4 = (const float4*)t2s512;

    // ---- pass 1: screen min over all 512 codes ----
    float m = FLT_MAX;
    for (int t = 0; t < 32; ++t) {
        f16x8 a0 = embA[(t * 2 + 0) * 64 + lane];
        f16x8 a1 = embA[(t * 2 + 1) * 64 + lane];
        f32x4 c = __builtin_amdgcn_mfma_f32_16x16x32_f16(a0, b0, czero, 0, 0, 0);
        c = __builtin_amdgcn_mfma_f32_16x16x32_f16(a1, b1, c, 0, 0, 0);
        float4 tv = t2s4[t * 4 + bg];
        float s0 = fmaf(-2.f, c[0], tv.x);
        float s1 = fmaf(-2.f, c[1], tv.y);
        float s2 = fmaf(-2.f, c[2], tv.z);
        float s3 = fmaf(-2.f, c[3], tv.w);
        m = fminf(m, fminf(fminf(s0, s1), fminf(s2, s3)));
    }
    m = fminf(m, __shfl_xor(m, 16));
    m = fminf(m, __shfl_xor(m, 32));
    const float thr = m + W_SCR;                // per-pixel threshold

    // ---- pass 2: recompute screen, COLLECT candidates ----
    for (int t = 0; t < 32; ++t) {
        f16x8 a0 = embA[(t * 2 + 0) * 64 + lane];
        f16x8 a1 = embA[(t * 2 + 1) * 64 + lane];
        f32x4 c = __builtin_amdgcn_mfma_f32_16x16x32_f16(a0, b0, czero, 0, 0, 0);
        c = __builtin_amdgcn_mfma_f32_16x16x32_f16(a1, b1, c, 0, 0, 0);
        float4 tv = t2s4[t * 4 + bg];
        #pragma unroll
        for (int j = 0; j < 4; ++j) {
            float sj = fmaf(-2.f, c[j], (j == 0) ? tv.x : (j == 1) ? tv.y
                                       : (j == 2) ? tv.z : tv.w);
            if (sj < thr) {
                const int k = t * 16 + bg * 4 + j;
                int slot = atomicAdd(&lcnt, 1);
                if (slot < LCAP) list[slot] = bp * 512 + k;
            }
        }
    }
    __syncthreads();

    // ---- rescue: one candidate per lane, operands from LDS ----
    const int ncand = min(lcnt, LCAP);
    for (int i = tid; i < ncand; i += 256) {
        const int v = list[i];
        const int p = v >> 9;
        const int k = v & 511;
        const float* xp = &xf[p * XROW];
        const float* __restrict__ ep = emb + (k << 6);
        float a = 0.f;
        #pragma unroll
        for (int d = 0; d < D_EMB; ++d) a = fmaf(xp[d], ep[d], a);
        float X = t1s[p] + t2[k];
        float dnp = fmaf(-2.f, a, X);           // exact np-f32 dist
        unsigned long long key =
            ((unsigned long long)__float_as_uint(dnp) << 32) | (unsigned)k;
        atomicMin(&keys[p], key);
    }
    __syncthreads();

    // ---- epilogue: thread (p,q); x from LDS, quantized out, loss partial ----
    float acc = 0.f;
    {
        const int p = tid & 63;
        const int q = tid >> 6;
        const int n2 = blockIdx.x * 64 + p;
        const int kw = (int)(unsigned)(keys[p] & 0xFFFFFFFFull);
        float* __restrict__ qp = out_q + (n2 >> 10) * 65536 + (n2 & 1023);
        const float4* __restrict__ eq = (const float4*)(emb + (kw << 6) + q * 16);
        #pragma unroll
        for (int j4 = 0; j4 < 4; ++j4) {
            float4 qv = eq[j4];
            const int d = q * 16 + j4 * 4;
            float f0 = qv.x - xf[p * XROW + d + 0];
            float f1 = qv.y - xf[p * XROW + d + 1];
            float f2 = qv.z - xf[p * XROW + d + 2];
            float f3 = qv.w - xf[p * XROW + d + 3];
            acc = fmaf(f0, f0, acc);
            acc = fmaf(f1, f1, acc);
            acc = fmaf(f2, f2, acc);
            acc = fmaf(f3, f3, acc);
            qp[(d + 0) * 1024] = qv.x;
            qp[(d + 1) * 1024] = qv.y;
            qp[(d + 2) * 1024] = qv.z;
            qp[(d + 3) * 1024] = qv.w;
        }
        if (q == 0) out_idx[n2] = (float)kw;
    }

    // block loss partial
    #pragma unroll
    for (int off = 32; off > 0; off >>= 1) acc += __shfl_down(acc, off);
    if (lane == 0) red[wave] = acc;
    __syncthreads();
    if (tid == 0)
        partial[blockIdx.x] = (red[0] + red[1]) + (red[2] + red[3]);
}

// ---------------- kernel 3: finalize loss over 1024 partials ----------------
__global__ __launch_bounds__(256) void vq_loss(const float* __restrict__ partial,
                                               float* __restrict__ loss) {
    const int t = threadIdx.x;
    float v = (partial[t] + partial[t + 256]) + (partial[t + 512] + partial[t + 768]);
    #pragma unroll
    for (int off = 32; off > 0; off >>= 1) v += __shfl_down(v, off);
    __shared__ float red[4];
    if ((t & 63) == 0) red[t >> 6] = v;
    __syncthreads();
    if (t == 0)
        loss[0] = 1.25f * ((red[0] + red[1]) + (red[2] + red[3])) / (float)Q_ELEMS;
}

extern "C" void kernel_launch(void* const* d_in, const int* in_sizes, int n_in,
                              void* d_out, int out_size, void* d_ws, size_t ws_size,
                              hipStream_t stream) {
    const float* x   = (const float*)d_in[0];   // [64,64,32,32] NCHW
    const float* emb = (const float*)d_in[1];   // [512,64]

    float* out_q    = (float*)d_out;                // [4194304]
    float* out_loss = (float*)d_out + Q_ELEMS;      // [1]
    float* out_idx  = (float*)d_out + Q_ELEMS + 1;  // [65536] as float

    float* t2      = (float*)d_ws;                  // 512
    float* t2s512  = t2 + K_EMB;                    // 512
    float* partial = t2s512 + K_EMB;                // 1024
    f16x8* embA    = (f16x8*)(partial + 1024);      // 4096 * 16B = 64KB

    vq_prep<<<16, 256, 0, stream>>>(emb, t2, t2s512, embA);
    vq_main<<<NBLK, 256, 0, stream>>>(x, emb, t2, t2s512, embA,
                                      out_q, out_idx, partial);
    vq_loss<<<1, 256, 0, stream>>>(partial, out_loss);
}